// Round 6
// baseline (8660.667 us; speedup 1.0000x reference)
//
#include <hip/hip_runtime.h>
#include <hip/hip_fp16.h>

// ---------------------------------------------------------------------------
// GPN_GCN: fat kernel (GEMM1 MFMA + edge-count atomics; atomic cost is a
// fixed memory-side floor — see R3/R4 post-mortems) -> block-staged
// segmented-SpMM props (64 dst nodes/block, contiguous CSR range, 4-deep
// gather pipeline, LDS f32 atomic accumulation) for GCN props + APPNP(10)
// -> fused MFMA classifier -> log_softmax fused into last APPNP step.
// R5 resubmit: hardened segment-walk (cur clamped; je clamped) — converts
// any CSR inconsistency from a hang into a terminating access.
// ---------------------------------------------------------------------------

struct __align__(16) half8 { __half2 h[4]; };
typedef _Float16 f16x8 __attribute__((ext_vector_type(8)));
typedef float f32x4 __attribute__((ext_vector_type(4)));

__device__ __forceinline__ f16x8 cvt8(const float4& a, const float4& b) {
    f16x8 r;
    r[0] = (_Float16)a.x; r[1] = (_Float16)a.y; r[2] = (_Float16)a.z; r[3] = (_Float16)a.w;
    r[4] = (_Float16)b.x; r[5] = (_Float16)b.y; r[6] = (_Float16)b.z; r[7] = (_Float16)b.w;
    return r;
}

__global__ __launch_bounds__(256) void k_scanA(const int* __restrict__ deg, int* bs, int N) {
    __shared__ int s[256];
    int t = threadIdx.x;
    int i = blockIdx.x * 256 + t;
    int c = (i < N) ? deg[i] : 0;
    s[t] = c; __syncthreads();
    for (int o = 128; o > 0; o >>= 1) {
        if (t < o) s[t] += s[t + o];
        __syncthreads();
    }
    if (t == 0) bs[blockIdx.x] = s[0];
}

__global__ __launch_bounds__(512) void k_scanB(int* bs, int NB) {
    __shared__ int s[512];
    int t = threadIdx.x;
    int v = (t < NB) ? bs[t] : 0;
    s[t] = v; __syncthreads();
    for (int o = 1; o < 512; o <<= 1) {
        int u = (t >= o) ? s[t - o] : 0;
        __syncthreads();
        s[t] += u;
        __syncthreads();
    }
    if (t < NB) bs[t] = s[t] - v;  // exclusive
}

__global__ __launch_bounds__(256) void k_scanC(const int* __restrict__ deg, const int* __restrict__ bs,
                                               int* row_ptr, float* dinv, int N) {
    __shared__ int s[256];
    int t = threadIdx.x;
    int i = blockIdx.x * 256 + t;
    int c = (i < N) ? deg[i] : 0;
    s[t] = c; __syncthreads();
    for (int o = 1; o < 256; o <<= 1) {
        int u = (t >= o) ? s[t - o] : 0;
        __syncthreads();
        s[t] += u;
        __syncthreads();
    }
    if (i < N) {
        int off = bs[blockIdx.x];
        row_ptr[i] = off + s[t] - c;            // exclusive (edges only)
        dinv[i] = rsqrtf((float)(deg[i] + 1));  // +1 = self loop
        if (i == N - 1) row_ptr[N] = off + s[t];
    }
}

// Atomic-free fill using precomputed ranks.
__global__ __launch_bounds__(256) void k_fill(const int* __restrict__ src, const int* __restrict__ dst,
                                              const int* __restrict__ row_ptr,
                                              const int* __restrict__ rank,
                                              int* __restrict__ csr_src, int E) {
    int e = blockIdx.x * 256 + threadIdx.x;
    if (e < E) csr_src[row_ptr[dst[e]] + rank[e]] = src[e];
}

// One merged prep kernel: blocks [0,128) -> W1t frag-major; [128,192) ->
// W2t frag-major; block 192 -> Wft = f16 frag-major (Wc@We), bf = bc@We+be.
__global__ __launch_bounds__(256) void k_prep(const float* __restrict__ W1,
                                              const float* __restrict__ W2,
                                              const float* __restrict__ Wc,
                                              const float* __restrict__ bc,
                                              const float* __restrict__ We,
                                              const float* __restrict__ be,
                                              __half* __restrict__ W1t,
                                              __half* __restrict__ W2t,
                                              __half* __restrict__ Wft,
                                              float* __restrict__ bf) {
    __shared__ float sWe[64 * 64];
    const int b = blockIdx.x, tid = threadIdx.x;
    if (b < 128) {           // W1t: K=256, NCOL=128
        int idx = b * 256 + tid;
        int j = idx & 7, n = (idx >> 3) & 127, qk = idx >> 10;
        int quad = qk & 3, kc = qk >> 2;
        int k = kc * 32 + quad * 8 + j;
        W1t[idx] = __float2half(W1[k * 128 + n]);
    } else if (b < 192) {    // W2t: K=128, NCOL=128
        int idx = (b - 128) * 256 + tid;
        int j = idx & 7, n = (idx >> 3) & 127, qk = idx >> 10;
        int quad = qk & 3, kc = qk >> 2;
        int k = kc * 32 + quad * 8 + j;
        W2t[idx] = __float2half(W2[k * 128 + n]);
    } else {                 // fuse: Wft (f16 frag-major) + bf
        for (int i = tid; i < 64 * 64 / 4; i += 256)
            ((float4*)sWe)[i] = ((const float4*)We)[i];
        __syncthreads();
        for (int idx = tid; idx < 128 * 64; idx += 256) {
            int r = idx >> 6, c = idx & 63;
            float s = 0.f;
#pragma unroll 8
            for (int j = 0; j < 64; j++) s += Wc[r * 64 + j] * sWe[j * 64 + c];
            int kc = r >> 5, quad = (r >> 3) & 3, jj = r & 7;
            Wft[(((kc * 4 + quad) * 64) + c) * 8 + jj] = __float2half(s);
        }
        if (tid < 64) {
            float s = be[tid];
#pragma unroll 8
            for (int j = 0; j < 64; j++) s += bc[j] * sWe[j * 64 + tid];
            bf[tid] = s;
        }
    }
}

// MFMA GEMM (+ fused edge-count). See R3/R4 notes: the 1.6M device-scope
// atomics are a fixed ~68us memory-side floor; fusing them here at least
// removes a separate dispatch and overlaps their issue latency.
template <int K, bool IN_F16, bool COUNT>
__global__ __launch_bounds__(512, 4) void k_gemm(const void* __restrict__ Xv,
                                                 const __half* __restrict__ Wtf,
                                                 const float* __restrict__ dinv,
                                                 __half* __restrict__ Y, int N,
                                                 const int* __restrict__ dst,
                                                 int* __restrict__ deg,
                                                 int* __restrict__ rank,
                                                 int E) {
    constexpr int NK = K / 32;
    constexpr int ITER = K / 32;
    __shared__ __align__(16) __half sB[K * 128];

    const int tid = threadIdx.x;

    // ---- fused edge-count: issue-early ----
    int r4[4];
    int ebase = 0, estr = 0;
    if constexpr (COUNT) {
        ebase = blockIdx.x * 512 + tid;
        estr  = gridDim.x * 512;
        int d4[4];
#pragma unroll
        for (int i = 0; i < 4; ++i) {
            int e = ebase + i * estr;
            d4[i] = (e < E) ? dst[e] : 0;
        }
#pragma unroll
        for (int i = 0; i < 4; ++i) {
            int e = ebase + i * estr;
            r4[i] = (e < E) ? atomicAdd(&deg[d4[i]], 1) : 0;
        }
        for (int e = ebase + 4 * estr; e < E; e += estr)
            rank[e] = atomicAdd(&deg[dst[e]], 1);
    }

    const int wv = tid >> 6, ln = tid & 63;
    const int m = ln & 15, quad = ln >> 4;
    const int rowBase = blockIdx.x * 128 + wv * 16;
    int rowA = rowBase + m;
    if (rowA > N - 1) rowA = N - 1;

    const float*  xf = (const float*)Xv;
    const __half* xh = (const __half*)Xv;
    const long aOff = (long)rowA * K + quad * 8;

    f16x8 a8[4];
    float4 t0[4], t1[4];
    if constexpr (IN_F16) {
#pragma unroll
        for (int kc = 0; kc < NK; ++kc)
            a8[kc] = *(const f16x8*)&xh[aOff + kc * 32];
    } else {
#pragma unroll
        for (int c = 0; c < 4; ++c) {
            t0[c] = *(const float4*)&xf[aOff + c * 32];
            t1[c] = *(const float4*)&xf[aOff + c * 32 + 4];
        }
    }

    {
        f16x8 tb[ITER];
        const f16x8* g = (const f16x8*)Wtf;
#pragma unroll
        for (int i = 0; i < ITER; ++i) tb[i] = g[(i * 8 + wv) * 64 + ln];
        f16x8* l = (f16x8*)sB;
#pragma unroll
        for (int i = 0; i < ITER; ++i) l[(i * 8 + wv) * 64 + ln] = tb[i];
    }
    __syncthreads();

    if constexpr (!IN_F16) {
#pragma unroll
        for (int c = 0; c < 4; ++c) a8[c] = cvt8(t0[c], t1[c]);
#pragma unroll
        for (int c = 0; c < 4; ++c) {
            t0[c] = *(const float4*)&xf[aOff + (c + 4) * 32];
            t1[c] = *(const float4*)&xf[aOff + (c + 4) * 32 + 4];
        }
    }

    f32x4 d[8];
#pragma unroll
    for (int ct = 0; ct < 8; ++ct) d[ct] = {0.f, 0.f, 0.f, 0.f};

#pragma unroll
    for (int h = 0; h < NK / 4; ++h) {
        if constexpr (!IN_F16) {
            if (h == 1) {
#pragma unroll
                for (int c = 0; c < 4; ++c) a8[c] = cvt8(t0[c], t1[c]);
            }
        }
#pragma unroll
        for (int kq = 0; kq < 4; ++kq) {
            const int kc = h * 4 + kq;
            const f16x8 a = a8[IN_F16 ? kc : kq];
            const __half* bb = &sB[(size_t)(kc * 4 + quad) * 128 * 8];
#pragma unroll
            for (int ct = 0; ct < 8; ++ct) {
                const f16x8 b = *(const f16x8*)&bb[(ct * 16 + m) * 8];
                d[ct] = __builtin_amdgcn_mfma_f32_16x16x32_f16(a, b, d[ct], 0, 0, 0);
            }
        }
    }

#pragma unroll
    for (int ct = 0; ct < 8; ++ct) {
        const int col = ct * 16 + m;
#pragma unroll
        for (int reg = 0; reg < 4; ++reg) {
            const int row = rowBase + quad * 4 + reg;
            if (row < N) {
                if constexpr (COUNT)
                    Y[(long)row * 128 + col] = __float2half(d[ct][reg]);
                else
                    Y[(long)row * 128 + col] = __float2half(d[ct][reg] * dinv[row]);
            }
        }
    }

    if constexpr (COUNT) {
#pragma unroll
        for (int i = 0; i < 4; ++i) {
            int e = ebase + i * estr;
            if (e < E) rank[e] = r4[i];
        }
    }
}

// Fused classifier via MFMA (f16 input): ev(f32) = relu(H @ Wf + bf);
// evs(f16) = dinv (.) ev.
__global__ __launch_bounds__(512, 4) void k_cls(const __half* __restrict__ H,
                                                const __half* __restrict__ Wtf,
                                                const float* __restrict__ bf,
                                                const float* __restrict__ dinv,
                                                float* __restrict__ ev,
                                                __half* __restrict__ evs, int N) {
    __shared__ __align__(16) __half sB[128 * 64];
    const int tid = threadIdx.x;
    const int wv = tid >> 6, ln = tid & 63;
    const int m = ln & 15, quad = ln >> 4;
    const int rowBase = blockIdx.x * 128 + wv * 16;
    int rowA = rowBase + m;
    if (rowA > N - 1) rowA = N - 1;
    const long aOff = (long)rowA * 128 + quad * 8;

    f16x8 a8[4];
#pragma unroll
    for (int kc = 0; kc < 4; ++kc)
        a8[kc] = *(const f16x8*)&H[aOff + kc * 32];

    {
        f16x8 tb[2];
        const f16x8* g = (const f16x8*)Wtf;
#pragma unroll
        for (int i = 0; i < 2; ++i) tb[i] = g[(i * 8 + wv) * 64 + ln];
        f16x8* l = (f16x8*)sB;
#pragma unroll
        for (int i = 0; i < 2; ++i) l[(i * 8 + wv) * 64 + ln] = tb[i];
    }
    __syncthreads();

    f32x4 d[4];
#pragma unroll
    for (int ct = 0; ct < 4; ++ct) d[ct] = {0.f, 0.f, 0.f, 0.f};

#pragma unroll
    for (int kc = 0; kc < 4; ++kc) {
        const __half* bb = &sB[(size_t)(kc * 4 + quad) * 64 * 8];
#pragma unroll
        for (int ct = 0; ct < 4; ++ct) {
            const f16x8 b = *(const f16x8*)&bb[(ct * 16 + m) * 8];
            d[ct] = __builtin_amdgcn_mfma_f32_16x16x32_f16(a8[kc], b, d[ct], 0, 0, 0);
        }
    }

#pragma unroll
    for (int ct = 0; ct < 4; ++ct) {
        const int col = ct * 16 + m;
#pragma unroll
        for (int reg = 0; reg < 4; ++reg) {
            const int row = rowBase + quad * 4 + reg;
            if (row < N) {
                float v = fmaxf(d[ct][reg] + bf[col], 0.f);
                ev[(long)row * 64 + col] = v;
                evs[(long)row * 64 + col] = __float2half(v * dinv[row]);
            }
        }
    }
}

// ---------------------------------------------------------------------------
// Block-staged segmented-SpMM propagation. One block = 64 consecutive dst
// nodes -> ONE contiguous CSR edge range (~1024 edges avg). 65 row_ptrs in
// LDS; range split into NSLOT per-slot chunks; each slot streams its chunk
// with a 4-deep gather pipeline (indices prefetched one quartet ahead).
// Per-edge f32 accumulation via LDS atomicAdd into a padded [64][F] tile
// (edges sorted by dst -> low contention). Epilogue: 4 threads/node read
// the tile row, add the self-loop term, apply the mode math.
// MODE 4 (GCN l1, unscaled tab): out f16 = relu(di*(sum dinv[s]*tab[s] + di*tab[n]) + b)
// MODE 3 (GCN l2, scaled tab):   out f16 = relu(di*(sum tab[s] + tab[n]) + b)
// MODE 1 (APPNP inner, scaled):  out f16 = 0.9*di^2*A + 0.1*evs[n]
// MODE 2 (APPNP final):          out f32 = log_softmax(0.9*di*A + 0.1*ev[n])
// ---------------------------------------------------------------------------
template <int F, int MODE>
__global__ __launch_bounds__(256) void k_prop3(const __half* __restrict__ tab,
                                               const int* __restrict__ row_ptr,
                                               const int* __restrict__ csr_src,
                                               const float* __restrict__ dinv,
                                               const float* __restrict__ bias,
                                               const void* __restrict__ evx,
                                               void* __restrict__ out, int N) {
    constexpr int LPE = F / 8;           // lanes per edge (half8 = 16B each)
    constexpr int NSLOT = 256 / LPE;     // 32 (F=64) / 16 (F=128)
    constexpr int STRIDE = F + 4;        // LDS row stride (floats): spreads banks
    __shared__ __align__(16) float sacc[64 * STRIDE];
    __shared__ int srp[65];

    const int tid = threadIdx.x;
    const int n0 = blockIdx.x * 64;

    for (int i = tid; i < 64 * STRIDE; i += 256) sacc[i] = 0.f;
    if (tid < 65) {
        int nn = n0 + tid; if (nn > N) nn = N;
        srp[tid] = row_ptr[nn];
    }
    __syncthreads();

    const int base = srp[0], end = srp[64];
    const int range = end - base;
    const int chunk = (range + NSLOT - 1) / NSLOT;
    const int slot = tid / LPE;
    const int fl = tid % LPE;
    int j = base + slot * chunk;
    int je = j + chunk;
    if (je > end) je = end;
    if (j < base) j = base;              // defensive (chunk>=0 so no-op)

    if (j < je) {
        // binary search: cur s.t. srp[cur] <= j < srp[cur+1]
        int lo = 0, hi = 64;
        while (hi - lo > 1) { int mid = (lo + hi) >> 1; if (srp[mid] <= j) lo = mid; else hi = mid; }
        int cur = lo;

        auto addE = [&](const half8& g, int c_, float dv) {
            float* dstp = &sacc[c_ * STRIDE + 8 * fl];
#pragma unroll
            for (int k = 0; k < 4; ++k) {
                float2 f2 = __half22float2(g.h[k]);
                if (MODE == 4) { f2.x *= dv; f2.y *= dv; }
                atomicAdd(&dstp[2 * k],     f2.x);
                atomicAdd(&dstp[2 * k + 1], f2.y);
            }
        };

        // prologue: first index quartet
        int cnt = je - j;
        int i0 = csr_src[j];
        int i1 = (cnt > 1) ? csr_src[j + 1] : 0;
        int i2 = (cnt > 2) ? csr_src[j + 2] : 0;
        int i3 = (cnt > 3) ? csr_src[j + 3] : 0;

        while (j < je) {
            const int c = je - j;
            half8 g0, g1, g2, g3;
            float dv0 = 1.f, dv1 = 1.f, dv2 = 1.f, dv3 = 1.f;
            g0 = *(const half8*)&tab[(long)i0 * F + 8 * fl];
            if (MODE == 4) dv0 = dinv[i0];
            if (c > 1) { g1 = *(const half8*)&tab[(long)i1 * F + 8 * fl]; if (MODE == 4) dv1 = dinv[i1]; }
            if (c > 2) { g2 = *(const half8*)&tab[(long)i2 * F + 8 * fl]; if (MODE == 4) dv2 = dinv[i2]; }
            if (c > 3) { g3 = *(const half8*)&tab[(long)i3 * F + 8 * fl]; if (MODE == 4) dv3 = dinv[i3]; }
            // prefetch next quartet's indices while gathers are in flight
            const int nj = j + 4;
            const int nc = je - nj;
            int p0 = 0, p1 = 0, p2 = 0, p3 = 0;
            if (nc > 0) p0 = csr_src[nj];
            if (nc > 1) p1 = csr_src[nj + 1];
            if (nc > 2) p2 = csr_src[nj + 2];
            if (nc > 3) p3 = csr_src[nj + 3];
            // consume (advance dst pointer per edge; edges sorted by dst).
            // cur clamped to 63: with a consistent CSR the clamp never
            // binds (j < end = srp[64]); with a corrupt one it prevents
            // an unbounded walk (hang) — see R5 post-mortem.
            while (cur < 63 && j >= srp[cur + 1]) ++cur;
            addE(g0, cur, dv0);
            if (c > 1) { while (cur < 63 && j + 1 >= srp[cur + 1]) ++cur; addE(g1, cur, dv1); }
            if (c > 2) { while (cur < 63 && j + 2 >= srp[cur + 1]) ++cur; addE(g2, cur, dv2); }
            if (c > 3) { while (cur < 63 && j + 3 >= srp[cur + 1]) ++cur; addE(g3, cur, dv3); }
            i0 = p0; i1 = p1; i2 = p2; i3 = p3;
            j = nj;
        }
    }
    __syncthreads();

    // ---- epilogue: 4 threads per node ----
    const int node = tid >> 2, q = tid & 3;
    const int gn = n0 + node;
    if (gn >= N) return;
    constexpr int FPT = F / 4;           // feats per thread: 16 / 32
    const float* ap = &sacc[node * STRIDE + q * FPT];
    const float di = dinv[gn];
    const __half* selfp = &tab[(long)gn * F + q * FPT];

    if (MODE == 3 || MODE == 4) {
        __half* op = (__half*)out + (long)gn * F + q * FPT;
        const float* bp = bias + q * FPT;
        const float ss = (MODE == 4) ? di : 1.f;
#pragma unroll
        for (int g8 = 0; g8 < FPT / 8; ++g8) {
            const float4 a0 = *(const float4*)&ap[g8 * 8];
            const float4 a1 = *(const float4*)&ap[g8 * 8 + 4];
            const half8 sh = *(const half8*)&selfp[g8 * 8];
            const float4 b0 = *(const float4*)&bp[g8 * 8];
            const float4 b1 = *(const float4*)&bp[g8 * 8 + 4];
            const float2 s01 = __half22float2(sh.h[0]);
            const float2 s23 = __half22float2(sh.h[1]);
            const float2 s45 = __half22float2(sh.h[2]);
            const float2 s67 = __half22float2(sh.h[3]);
            half8 ov;
            ov.h[0] = __floats2half2_rn(fmaxf(di * (a0.x + ss * s01.x) + b0.x, 0.f),
                                        fmaxf(di * (a0.y + ss * s01.y) + b0.y, 0.f));
            ov.h[1] = __floats2half2_rn(fmaxf(di * (a0.z + ss * s23.x) + b0.z, 0.f),
                                        fmaxf(di * (a0.w + ss * s23.y) + b0.w, 0.f));
            ov.h[2] = __floats2half2_rn(fmaxf(di * (a1.x + ss * s45.x) + b1.x, 0.f),
                                        fmaxf(di * (a1.y + ss * s45.y) + b1.y, 0.f));
            ov.h[3] = __floats2half2_rn(fmaxf(di * (a1.z + ss * s67.x) + b1.z, 0.f),
                                        fmaxf(di * (a1.w + ss * s67.y) + b1.w, 0.f));
            *(half8*)&op[g8 * 8] = ov;
        }
    } else if (MODE == 1) {
        __half* op = (__half*)out + (long)gn * F + q * FPT;
        const __half* ep = (const __half*)evx + (long)gn * F + q * FPT;
        const float d2 = 0.9f * di * di;
#pragma unroll
        for (int g8 = 0; g8 < FPT / 8; ++g8) {
            const float4 a0 = *(const float4*)&ap[g8 * 8];
            const float4 a1 = *(const float4*)&ap[g8 * 8 + 4];
            const half8 sh = *(const half8*)&selfp[g8 * 8];
            const half8 eh = *(const half8*)&ep[g8 * 8];
            const float2 s01 = __half22float2(sh.h[0]);
            const float2 s23 = __half22float2(sh.h[1]);
            const float2 s45 = __half22float2(sh.h[2]);
            const float2 s67 = __half22float2(sh.h[3]);
            const float2 e01 = __half22float2(eh.h[0]);
            const float2 e23 = __half22float2(eh.h[1]);
            const float2 e45 = __half22float2(eh.h[2]);
            const float2 e67 = __half22float2(eh.h[3]);
            half8 ov;
            ov.h[0] = __floats2half2_rn(d2 * (a0.x + s01.x) + 0.1f * e01.x,
                                        d2 * (a0.y + s01.y) + 0.1f * e01.y);
            ov.h[1] = __floats2half2_rn(d2 * (a0.z + s23.x) + 0.1f * e23.x,
                                        d2 * (a0.w + s23.y) + 0.1f * e23.y);
            ov.h[2] = __floats2half2_rn(d2 * (a1.x + s45.x) + 0.1f * e45.x,
                                        d2 * (a1.y + s45.y) + 0.1f * e45.y);
            ov.h[3] = __floats2half2_rn(d2 * (a1.z + s67.x) + 0.1f * e67.x,
                                        d2 * (a1.w + s67.y) + 0.1f * e67.y);
            *(half8*)&op[g8 * 8] = ov;
        }
    } else {  // MODE 2: final APPNP + log_softmax (F==64, FPT==16)
        const float* ep = (const float*)evx + (long)gn * 64 + q * 16;
        float* op = (float*)out + (long)gn * 64 + q * 16;
        const float d1 = 0.9f * di;
        float v[16];
#pragma unroll
        for (int g8 = 0; g8 < 2; ++g8) {
            const float4 a0 = *(const float4*)&ap[g8 * 8];
            const float4 a1 = *(const float4*)&ap[g8 * 8 + 4];
            const half8 sh = *(const half8*)&selfp[g8 * 8];
            const float4 e0 = *(const float4*)&ep[g8 * 8];
            const float4 e1 = *(const float4*)&ep[g8 * 8 + 4];
            const float2 s01 = __half22float2(sh.h[0]);
            const float2 s23 = __half22float2(sh.h[1]);
            const float2 s45 = __half22float2(sh.h[2]);
            const float2 s67 = __half22float2(sh.h[3]);
            v[g8 * 8 + 0] = d1 * (a0.x + s01.x) + 0.1f * e0.x;
            v[g8 * 8 + 1] = d1 * (a0.y + s01.y) + 0.1f * e0.y;
            v[g8 * 8 + 2] = d1 * (a0.z + s23.x) + 0.1f * e0.z;
            v[g8 * 8 + 3] = d1 * (a0.w + s23.y) + 0.1f * e0.w;
            v[g8 * 8 + 4] = d1 * (a1.x + s45.x) + 0.1f * e1.x;
            v[g8 * 8 + 5] = d1 * (a1.y + s45.y) + 0.1f * e1.y;
            v[g8 * 8 + 6] = d1 * (a1.z + s67.x) + 0.1f * e1.z;
            v[g8 * 8 + 7] = d1 * (a1.w + s67.y) + 0.1f * e1.w;
        }
        float m = v[0];
#pragma unroll
        for (int k = 1; k < 16; ++k) m = fmaxf(m, v[k]);
        m = fmaxf(m, __shfl_xor(m, 1, 64));
        m = fmaxf(m, __shfl_xor(m, 2, 64));
        float ssum = 0.f;
#pragma unroll
        for (int k = 0; k < 16; ++k) ssum += __expf(v[k] - m);
        ssum += __shfl_xor(ssum, 1, 64);
        ssum += __shfl_xor(ssum, 2, 64);
        const float lse = m + __logf(ssum);
        float4 w0, w1, w2, w3;
        w0.x = v[0] - lse;  w0.y = v[1] - lse;  w0.z = v[2] - lse;  w0.w = v[3] - lse;
        w1.x = v[4] - lse;  w1.y = v[5] - lse;  w1.z = v[6] - lse;  w1.w = v[7] - lse;
        w2.x = v[8] - lse;  w2.y = v[9] - lse;  w2.z = v[10] - lse; w2.w = v[11] - lse;
        w3.x = v[12] - lse; w3.y = v[13] - lse; w3.z = v[14] - lse; w3.w = v[15] - lse;
        *(float4*)&op[0]  = w0;
        *(float4*)&op[4]  = w1;
        *(float4*)&op[8]  = w2;
        *(float4*)&op[12] = w3;
    }
}

extern "C" void kernel_launch(void* const* d_in, const int* in_sizes, int n_in,
                              void* d_out, int out_size, void* d_ws, size_t ws_size,
                              hipStream_t stream) {
    const float* x  = (const float*)d_in[0];
    const int* edges = (const int*)d_in[1];
    const float* W1 = (const float*)d_in[2];
    const float* b1 = (const float*)d_in[3];
    const float* W2 = (const float*)d_in[4];
    const float* b2 = (const float*)d_in[5];
    const float* Wc = (const float*)d_in[6];
    const float* bc = (const float*)d_in[7];
    const float* We = (const float*)d_in[8];
    const float* be = (const float*)d_in[9];

    const int N = in_sizes[0] / 256;   // 100000
    const int E = in_sizes[1] / 2;     // 1600000
    const int* esrc = edges;
    const int* edst = edges + E;

    char* ws = (char*)d_ws;
    size_t off = 0;
    auto alloc = [&](size_t bytes) -> void* {
        void* p = ws + off;
        off += (bytes + 255) & ~(size_t)255;
        return p;
    };
    int*    deg     = (int*)alloc((size_t)N * 4);
    int*    row_ptr = (int*)alloc((size_t)(N + 1) * 4);
    float*  dinv    = (float*)alloc((size_t)N * 4);
    int*    bs      = (int*)alloc(4096 * 4);
    int*    rank    = (int*)alloc((size_t)E * 4);
    int*    csr_src = (int*)alloc((size_t)E * 4);
    __half* P       = (__half*)alloc((size_t)N * 128 * 2);  // f16 table A
    __half* Q16     = (__half*)alloc((size_t)N * 128 * 2);  // f16 table B
    __half* zA      = (__half*)alloc((size_t)N * 64 * 2);
    __half* zB      = (__half*)alloc((size_t)N * 64 * 2);
    __half* evs     = (__half*)alloc((size_t)N * 64 * 2);
    float*  bf      = (float*)alloc(64 * 4);
    __half* W1t     = (__half*)alloc(128 * 256 * 2);  // fragment-major
    __half* W2t     = (__half*)alloc(128 * 128 * 2);  // fragment-major
    __half* Wft     = (__half*)alloc(64 * 128 * 2);   // fragment-major
    float*  ev      = (float*)d_out;  // f32 ev lives in d_out until final step

    const int nbN = (N + 255) / 256;
    const int nbE = (E + 255) / 256;
    const int nbB = (N + 63) / 64;      // segmented-SpMM prop blocks
    const int TG  = (N + 127) / 128;    // GEMM/cls blocks (128 rows each)

    // --- prep + fat kernel: GEMM1 (unscaled) with fused edge count ---
    hipMemsetAsync(deg, 0, (size_t)N * 4, stream);
    k_prep<<<193, 256, 0, stream>>>(W1, W2, Wc, bc, We, be, W1t, W2t, Wft, bf);
    k_gemm<256, false, true><<<TG, 512, 0, stream>>>(x, W1t, nullptr, P, N,
                                                     edst, deg, rank, E);

    // --- CSR build ---
    k_scanA<<<nbN, 256, 0, stream>>>(deg, bs, N);
    k_scanB<<<1, 512, 0, stream>>>(bs, nbN);
    k_scanC<<<nbN, 256, 0, stream>>>(deg, bs, row_ptr, dinv, N);
    k_fill<<<nbE, 256, 0, stream>>>(esrc, edst, row_ptr, rank, csr_src, E);

    // --- GCN layer 1 prop (per-edge dinv: MODE 4, P unscaled) ---
    k_prop3<128, 4><<<nbB, 256, 0, stream>>>(P, row_ptr, csr_src, dinv, b1, nullptr, Q16, N);

    // --- GCN layer 2: P = f16(dinv * Q16@W2) via MFMA; prop MODE 3 ---
    k_gemm<128, true, false><<<TG, 512, 0, stream>>>(Q16, W2t, dinv, P, N,
                                                     nullptr, nullptr, nullptr, 0);
    k_prop3<128, 3><<<nbB, 256, 0, stream>>>(P, row_ptr, csr_src, dinv, b2, nullptr, Q16, N);

    // --- fused classifier (MFMA): ev (f32, d_out) + evs (f16 scaled) ---
    k_cls<<<TG, 512, 0, stream>>>(Q16, Wft, bf, dinv, ev, evs, N);

    // --- APPNP: 9 scaled f16 iterations + final step fused w/ log_softmax ---
    const __half* zin = evs;
    __half* zout;
    for (int it = 0; it < 9; ++it) {
        zout = (it % 2 == 0) ? zA : zB;
        k_prop3<64, 1><<<nbB, 256, 0, stream>>>(zin, row_ptr, csr_src, dinv, nullptr, evs, zout, N);
        zin = zout;
    }
    // final: reads zA(f16) + ev(f32,d_out), writes log_softmax rows to d_out
    k_prop3<64, 2><<<nbB, 256, 0, stream>>>(zin, row_ptr, csr_src, dinv, nullptr, ev, (float*)d_out, N);
}

// Round 7
// 999.504 us; speedup vs baseline: 8.6650x; 8.6650x over previous
//
#include <hip/hip_runtime.h>
#include <hip/hip_fp16.h>

// ---------------------------------------------------------------------------
// GPN_GCN: fat kernel (GEMM1 MFMA with edge-count atomics fused in:
// issue-early / commit-late; the 1.6M device-scope atomics are a fixed
// ~68us coherence-point floor — R3/R4) -> GCN layer2 MFMA -> fused MFMA
// classifier (Wc@We collapsed) -> APPNP(10, f16 scaled tables) ->
// log_softmax fused into last step. Props: wave-per-node REGISTER
// accumulation (R6 disproved LDS-atomic segmented SpMM: 12x slower),
// now with a 4-deep gather pipeline per slot.
// ---------------------------------------------------------------------------

struct __align__(16) half8 { __half2 h[4]; };
typedef _Float16 f16x8 __attribute__((ext_vector_type(8)));
typedef float f32x4 __attribute__((ext_vector_type(4)));

__device__ __forceinline__ f16x8 cvt8(const float4& a, const float4& b) {
    f16x8 r;
    r[0] = (_Float16)a.x; r[1] = (_Float16)a.y; r[2] = (_Float16)a.z; r[3] = (_Float16)a.w;
    r[4] = (_Float16)b.x; r[5] = (_Float16)b.y; r[6] = (_Float16)b.z; r[7] = (_Float16)b.w;
    return r;
}

__global__ __launch_bounds__(256) void k_scanA(const int* __restrict__ deg, int* bs, int N) {
    __shared__ int s[256];
    int t = threadIdx.x;
    int i = blockIdx.x * 256 + t;
    int c = (i < N) ? deg[i] : 0;
    s[t] = c; __syncthreads();
    for (int o = 128; o > 0; o >>= 1) {
        if (t < o) s[t] += s[t + o];
        __syncthreads();
    }
    if (t == 0) bs[blockIdx.x] = s[0];
}

__global__ __launch_bounds__(512) void k_scanB(int* bs, int NB) {
    __shared__ int s[512];
    int t = threadIdx.x;
    int v = (t < NB) ? bs[t] : 0;
    s[t] = v; __syncthreads();
    for (int o = 1; o < 512; o <<= 1) {
        int u = (t >= o) ? s[t - o] : 0;
        __syncthreads();
        s[t] += u;
        __syncthreads();
    }
    if (t < NB) bs[t] = s[t] - v;  // exclusive
}

__global__ __launch_bounds__(256) void k_scanC(const int* __restrict__ deg, const int* __restrict__ bs,
                                               int* row_ptr, float* dinv, int N) {
    __shared__ int s[256];
    int t = threadIdx.x;
    int i = blockIdx.x * 256 + t;
    int c = (i < N) ? deg[i] : 0;
    s[t] = c; __syncthreads();
    for (int o = 1; o < 256; o <<= 1) {
        int u = (t >= o) ? s[t - o] : 0;
        __syncthreads();
        s[t] += u;
        __syncthreads();
    }
    if (i < N) {
        int off = bs[blockIdx.x];
        row_ptr[i] = off + s[t] - c;            // exclusive (edges only)
        dinv[i] = rsqrtf((float)(deg[i] + 1));  // +1 = self loop
        if (i == N - 1) row_ptr[N] = off + s[t];
    }
}

// Atomic-free fill using precomputed ranks.
__global__ __launch_bounds__(256) void k_fill(const int* __restrict__ src, const int* __restrict__ dst,
                                              const int* __restrict__ row_ptr,
                                              const int* __restrict__ rank,
                                              int* __restrict__ csr_src, int E) {
    int e = blockIdx.x * 256 + threadIdx.x;
    if (e < E) csr_src[row_ptr[dst[e]] + rank[e]] = src[e];
}

// One merged prep kernel: blocks [0,128) -> W1t frag-major; [128,192) ->
// W2t frag-major; block 192 -> Wft = f16 frag-major (Wc@We), bf = bc@We+be.
__global__ __launch_bounds__(256) void k_prep(const float* __restrict__ W1,
                                              const float* __restrict__ W2,
                                              const float* __restrict__ Wc,
                                              const float* __restrict__ bc,
                                              const float* __restrict__ We,
                                              const float* __restrict__ be,
                                              __half* __restrict__ W1t,
                                              __half* __restrict__ W2t,
                                              __half* __restrict__ Wft,
                                              float* __restrict__ bf) {
    __shared__ float sWe[64 * 64];
    const int b = blockIdx.x, tid = threadIdx.x;
    if (b < 128) {           // W1t: K=256, NCOL=128
        int idx = b * 256 + tid;
        int j = idx & 7, n = (idx >> 3) & 127, qk = idx >> 10;
        int quad = qk & 3, kc = qk >> 2;
        int k = kc * 32 + quad * 8 + j;
        W1t[idx] = __float2half(W1[k * 128 + n]);
    } else if (b < 192) {    // W2t: K=128, NCOL=128
        int idx = (b - 128) * 256 + tid;
        int j = idx & 7, n = (idx >> 3) & 127, qk = idx >> 10;
        int quad = qk & 3, kc = qk >> 2;
        int k = kc * 32 + quad * 8 + j;
        W2t[idx] = __float2half(W2[k * 128 + n]);
    } else {                 // fuse: Wft (f16 frag-major) + bf
        for (int i = tid; i < 64 * 64 / 4; i += 256)
            ((float4*)sWe)[i] = ((const float4*)We)[i];
        __syncthreads();
        for (int idx = tid; idx < 128 * 64; idx += 256) {
            int r = idx >> 6, c = idx & 63;
            float s = 0.f;
#pragma unroll 8
            for (int j = 0; j < 64; j++) s += Wc[r * 64 + j] * sWe[j * 64 + c];
            int kc = r >> 5, quad = (r >> 3) & 3, jj = r & 7;
            Wft[(((kc * 4 + quad) * 64) + c) * 8 + jj] = __float2half(s);
        }
        if (tid < 64) {
            float s = be[tid];
#pragma unroll 8
            for (int j = 0; j < 64; j++) s += bc[j] * sWe[j * 64 + tid];
            bf[tid] = s;
        }
    }
}

// MFMA GEMM (+ fused edge-count). R3/R4: the 1.6M device-scope atomics are
// a fixed ~68us memory-side floor; fusing them here removes a dispatch and
// overlaps their issue latency with the GEMM.
template <int K, bool IN_F16, bool COUNT>
__global__ __launch_bounds__(512, 4) void k_gemm(const void* __restrict__ Xv,
                                                 const __half* __restrict__ Wtf,
                                                 const float* __restrict__ dinv,
                                                 __half* __restrict__ Y, int N,
                                                 const int* __restrict__ dst,
                                                 int* __restrict__ deg,
                                                 int* __restrict__ rank,
                                                 int E) {
    constexpr int NK = K / 32;
    constexpr int ITER = K / 32;
    __shared__ __align__(16) __half sB[K * 128];

    const int tid = threadIdx.x;

    // ---- fused edge-count: issue-early ----
    int r4[4];
    int ebase = 0, estr = 0;
    if constexpr (COUNT) {
        ebase = blockIdx.x * 512 + tid;
        estr  = gridDim.x * 512;
        int d4[4];
#pragma unroll
        for (int i = 0; i < 4; ++i) {
            int e = ebase + i * estr;
            d4[i] = (e < E) ? dst[e] : 0;
        }
#pragma unroll
        for (int i = 0; i < 4; ++i) {
            int e = ebase + i * estr;
            r4[i] = (e < E) ? atomicAdd(&deg[d4[i]], 1) : 0;
        }
        for (int e = ebase + 4 * estr; e < E; e += estr)
            rank[e] = atomicAdd(&deg[dst[e]], 1);
    }

    const int wv = tid >> 6, ln = tid & 63;
    const int m = ln & 15, quad = ln >> 4;
    const int rowBase = blockIdx.x * 128 + wv * 16;
    int rowA = rowBase + m;
    if (rowA > N - 1) rowA = N - 1;

    const float*  xf = (const float*)Xv;
    const __half* xh = (const __half*)Xv;
    const long aOff = (long)rowA * K + quad * 8;

    f16x8 a8[4];
    float4 t0[4], t1[4];
    if constexpr (IN_F16) {
#pragma unroll
        for (int kc = 0; kc < NK; ++kc)
            a8[kc] = *(const f16x8*)&xh[aOff + kc * 32];
    } else {
#pragma unroll
        for (int c = 0; c < 4; ++c) {
            t0[c] = *(const float4*)&xf[aOff + c * 32];
            t1[c] = *(const float4*)&xf[aOff + c * 32 + 4];
        }
    }

    {
        f16x8 tb[ITER];
        const f16x8* g = (const f16x8*)Wtf;
#pragma unroll
        for (int i = 0; i < ITER; ++i) tb[i] = g[(i * 8 + wv) * 64 + ln];
        f16x8* l = (f16x8*)sB;
#pragma unroll
        for (int i = 0; i < ITER; ++i) l[(i * 8 + wv) * 64 + ln] = tb[i];
    }
    __syncthreads();

    if constexpr (!IN_F16) {
#pragma unroll
        for (int c = 0; c < 4; ++c) a8[c] = cvt8(t0[c], t1[c]);
#pragma unroll
        for (int c = 0; c < 4; ++c) {
            t0[c] = *(const float4*)&xf[aOff + (c + 4) * 32];
            t1[c] = *(const float4*)&xf[aOff + (c + 4) * 32 + 4];
        }
    }

    f32x4 d[8];
#pragma unroll
    for (int ct = 0; ct < 8; ++ct) d[ct] = {0.f, 0.f, 0.f, 0.f};

#pragma unroll
    for (int h = 0; h < NK / 4; ++h) {
        if constexpr (!IN_F16) {
            if (h == 1) {
#pragma unroll
                for (int c = 0; c < 4; ++c) a8[c] = cvt8(t0[c], t1[c]);
            }
        }
#pragma unroll
        for (int kq = 0; kq < 4; ++kq) {
            const int kc = h * 4 + kq;
            const f16x8 a = a8[IN_F16 ? kc : kq];
            const __half* bb = &sB[(size_t)(kc * 4 + quad) * 128 * 8];
#pragma unroll
            for (int ct = 0; ct < 8; ++ct) {
                const f16x8 b = *(const f16x8*)&bb[(ct * 16 + m) * 8];
                d[ct] = __builtin_amdgcn_mfma_f32_16x16x32_f16(a, b, d[ct], 0, 0, 0);
            }
        }
    }

#pragma unroll
    for (int ct = 0; ct < 8; ++ct) {
        const int col = ct * 16 + m;
#pragma unroll
        for (int reg = 0; reg < 4; ++reg) {
            const int row = rowBase + quad * 4 + reg;
            if (row < N) {
                if constexpr (COUNT)
                    Y[(long)row * 128 + col] = __float2half(d[ct][reg]);
                else
                    Y[(long)row * 128 + col] = __float2half(d[ct][reg] * dinv[row]);
            }
        }
    }

    if constexpr (COUNT) {
#pragma unroll
        for (int i = 0; i < 4; ++i) {
            int e = ebase + i * estr;
            if (e < E) rank[e] = r4[i];
        }
    }
}

// Fused classifier via MFMA (f16 input): ev(f32) = relu(H @ Wf + bf);
// evs(f16) = dinv (.) ev.
__global__ __launch_bounds__(512, 4) void k_cls(const __half* __restrict__ H,
                                                const __half* __restrict__ Wtf,
                                                const float* __restrict__ bf,
                                                const float* __restrict__ dinv,
                                                float* __restrict__ ev,
                                                __half* __restrict__ evs, int N) {
    __shared__ __align__(16) __half sB[128 * 64];
    const int tid = threadIdx.x;
    const int wv = tid >> 6, ln = tid & 63;
    const int m = ln & 15, quad = ln >> 4;
    const int rowBase = blockIdx.x * 128 + wv * 16;
    int rowA = rowBase + m;
    if (rowA > N - 1) rowA = N - 1;
    const long aOff = (long)rowA * 128 + quad * 8;

    f16x8 a8[4];
#pragma unroll
    for (int kc = 0; kc < 4; ++kc)
        a8[kc] = *(const f16x8*)&H[aOff + kc * 32];

    {
        f16x8 tb[2];
        const f16x8* g = (const f16x8*)Wtf;
#pragma unroll
        for (int i = 0; i < 2; ++i) tb[i] = g[(i * 8 + wv) * 64 + ln];
        f16x8* l = (f16x8*)sB;
#pragma unroll
        for (int i = 0; i < 2; ++i) l[(i * 8 + wv) * 64 + ln] = tb[i];
    }
    __syncthreads();

    f32x4 d[4];
#pragma unroll
    for (int ct = 0; ct < 4; ++ct) d[ct] = {0.f, 0.f, 0.f, 0.f};

#pragma unroll
    for (int kc = 0; kc < 4; ++kc) {
        const __half* bb = &sB[(size_t)(kc * 4 + quad) * 64 * 8];
#pragma unroll
        for (int ct = 0; ct < 4; ++ct) {
            const f16x8 b = *(const f16x8*)&bb[(ct * 16 + m) * 8];
            d[ct] = __builtin_amdgcn_mfma_f32_16x16x32_f16(a8[kc], b, d[ct], 0, 0, 0);
        }
    }

#pragma unroll
    for (int ct = 0; ct < 4; ++ct) {
        const int col = ct * 16 + m;
#pragma unroll
        for (int reg = 0; reg < 4; ++reg) {
            const int row = rowBase + quad * 4 + reg;
            if (row < N) {
                float v = fmaxf(d[ct][reg] + bf[col], 0.f);
                ev[(long)row * 64 + col] = v;
                evs[(long)row * 64 + col] = __float2half(v * dinv[row]);
            }
        }
    }
}

// Wave-per-node gather propagation over fp16 table, register accumulation,
// 4-deep gather pipeline per slot (gathers at j, j+S, j+2S, j+3S issued
// together; indices prefetched one quartet ahead).
// MODE 4 (GCN l1, unscaled tab): out = relu(di*(sum dinv[s]*tab[s] + di*tab[n]) + b)
// MODE 3 (GCN l2, scaled tab):   out = relu(di*A + bias)
// MODE 1 (APPNP inner, scaled):  out(f16) = 0.9*di^2*A + 0.1*evs[n]
// MODE 2 (APPNP final):          out(f32) = log_softmax(0.9*di*A + 0.1*ev[n])
template <int F, int MODE>
__global__ __launch_bounds__(256) void k_prop2(const __half* __restrict__ tab,
                                               const int* __restrict__ row_ptr,
                                               const int* __restrict__ csr_src,
                                               const float* __restrict__ dinv,
                                               const float* __restrict__ bias,
                                               const void* __restrict__ evx,
                                               void* __restrict__ out, int N) {
    constexpr int LPE = F / 8;    // lanes per edge-slot (half8 = 8 feats each)
    constexpr int S = 64 / LPE;   // edge slots per wave
    int wave = threadIdx.x >> 6;
    int lane = threadIdx.x & 63;
    int node = blockIdx.x * 4 + wave;
    if (node >= N) return;
    int slot = lane / LPE;
    int fl = lane % LPE;          // features 8*fl .. 8*fl+7
    const int2 se = *(const int2*)&row_ptr[node];
    int s = se.x, e = se.y;

    float acc[8], accB[8];
#pragma unroll
    for (int q = 0; q < 8; q++) { acc[q] = 0.f; accB[q] = 0.f; }

    int j = s + slot;
    int i0 = 0, i1 = 0, i2 = 0, i3 = 0;
    if (j < e)         i0 = csr_src[j];
    if (j + S < e)     i1 = csr_src[j + S];
    if (j + 2 * S < e) i2 = csr_src[j + 2 * S];
    if (j + 3 * S < e) i3 = csr_src[j + 3 * S];

    while (j + 3 * S < e) {
        // 4 gathers in flight
        const half8 a = *(const half8*)&tab[(long)i0 * F + 8 * fl];
        const half8 b = *(const half8*)&tab[(long)i1 * F + 8 * fl];
        const half8 c = *(const half8*)&tab[(long)i2 * F + 8 * fl];
        const half8 d = *(const half8*)&tab[(long)i3 * F + 8 * fl];
        float dv0 = 1.f, dv1 = 1.f, dv2 = 1.f, dv3 = 1.f;
        if (MODE == 4) { dv0 = dinv[i0]; dv1 = dinv[i1]; dv2 = dinv[i2]; dv3 = dinv[i3]; }
        // prefetch next quartet's indices while gathers are in flight
        const int jn = j + 4 * S;
        int p0 = 0, p1 = 0, p2 = 0, p3 = 0;
        if (jn < e)         p0 = csr_src[jn];
        if (jn + S < e)     p1 = csr_src[jn + S];
        if (jn + 2 * S < e) p2 = csr_src[jn + 2 * S];
        if (jn + 3 * S < e) p3 = csr_src[jn + 3 * S];
#pragma unroll
        for (int q = 0; q < 4; q++) {
            float2 fa = __half22float2(a.h[q]);
            float2 fb = __half22float2(b.h[q]);
            float2 fc = __half22float2(c.h[q]);
            float2 fd = __half22float2(d.h[q]);
            acc[2 * q]      += dv0 * fa.x + dv2 * fc.x;
            acc[2 * q + 1]  += dv0 * fa.y + dv2 * fc.y;
            accB[2 * q]     += dv1 * fb.x + dv3 * fd.x;
            accB[2 * q + 1] += dv1 * fb.y + dv3 * fd.y;
        }
        i0 = p0; i1 = p1; i2 = p2; i3 = p3;
        j = jn;
    }
    // tail: up to 3 remaining edges (indices i0..i2 already loaded, guarded)
    if (j < e) {
        const half8 a = *(const half8*)&tab[(long)i0 * F + 8 * fl];
        float dv = (MODE == 4) ? dinv[i0] : 1.f;
#pragma unroll
        for (int q = 0; q < 4; q++) {
            float2 fa = __half22float2(a.h[q]);
            acc[2 * q] += dv * fa.x; acc[2 * q + 1] += dv * fa.y;
        }
    }
    if (j + S < e) {
        const half8 b = *(const half8*)&tab[(long)i1 * F + 8 * fl];
        float dv = (MODE == 4) ? dinv[i1] : 1.f;
#pragma unroll
        for (int q = 0; q < 4; q++) {
            float2 fb = __half22float2(b.h[q]);
            accB[2 * q] += dv * fb.x; accB[2 * q + 1] += dv * fb.y;
        }
    }
    if (j + 2 * S < e) {
        const half8 c = *(const half8*)&tab[(long)i2 * F + 8 * fl];
        float dv = (MODE == 4) ? dinv[i2] : 1.f;
#pragma unroll
        for (int q = 0; q < 4; q++) {
            float2 fc = __half22float2(c.h[q]);
            acc[2 * q] += dv * fc.x; acc[2 * q + 1] += dv * fc.y;
        }
    }
    if (slot == 0) {  // self loop
        const half8 a = *(const half8*)&tab[(long)node * F + 8 * fl];
        float ds = (MODE == 4) ? dinv[node] : 1.f;
#pragma unroll
        for (int q = 0; q < 4; q++) {
            float2 fa = __half22float2(a.h[q]);
            acc[2 * q] += ds * fa.x; acc[2 * q + 1] += ds * fa.y;
        }
    }
#pragma unroll
    for (int q = 0; q < 8; q++) acc[q] += accB[q];

#pragma unroll
    for (int off = LPE; off < 64; off <<= 1) {
#pragma unroll
        for (int q = 0; q < 8; q++) acc[q] += __shfl_xor(acc[q], off, 64);
    }

    if (slot == 0) {
        float di = dinv[node];
        if (MODE == 3 || MODE == 4) {
            const float4 b0 = *(const float4*)&bias[8 * fl];
            const float4 b1 = *(const float4*)&bias[8 * fl + 4];
            half8 ov;
            ov.h[0] = __floats2half2_rn(fmaxf(di * acc[0] + b0.x, 0.f),
                                        fmaxf(di * acc[1] + b0.y, 0.f));
            ov.h[1] = __floats2half2_rn(fmaxf(di * acc[2] + b0.z, 0.f),
                                        fmaxf(di * acc[3] + b0.w, 0.f));
            ov.h[2] = __floats2half2_rn(fmaxf(di * acc[4] + b1.x, 0.f),
                                        fmaxf(di * acc[5] + b1.y, 0.f));
            ov.h[3] = __floats2half2_rn(fmaxf(di * acc[6] + b1.z, 0.f),
                                        fmaxf(di * acc[7] + b1.w, 0.f));
            *(half8*)&((__half*)out)[(long)node * F + 8 * fl] = ov;
        } else if (MODE == 1) {
            float d2 = 0.9f * di * di;
            const half8 eh = *(const half8*)&((const __half*)evx)[(long)node * F + 8 * fl];
            half8 ov;
#pragma unroll
            for (int q = 0; q < 4; q++) {
                float2 ef = __half22float2(eh.h[q]);
                float vx = d2 * acc[2 * q] + 0.1f * ef.x;
                float vy = d2 * acc[2 * q + 1] + 0.1f * ef.y;
                ov.h[q] = __floats2half2_rn(vx, vy);
            }
            *(half8*)&((__half*)out)[(long)node * F + 8 * fl] = ov;
        } else {
            // final APPNP step fused with log_softmax (F==64: lanes 0..7
            // of each wave hold the full 64-class row, 8 classes each)
            float d1 = 0.9f * di;
            const float* ef = (const float*)evx + (long)node * F + 8 * fl;
            const float4 e0 = *(const float4*)ef;
            const float4 e1 = *(const float4*)(ef + 4);
            float v[8];
            v[0] = d1 * acc[0] + 0.1f * e0.x;
            v[1] = d1 * acc[1] + 0.1f * e0.y;
            v[2] = d1 * acc[2] + 0.1f * e0.z;
            v[3] = d1 * acc[3] + 0.1f * e0.w;
            v[4] = d1 * acc[4] + 0.1f * e1.x;
            v[5] = d1 * acc[5] + 0.1f * e1.y;
            v[6] = d1 * acc[6] + 0.1f * e1.z;
            v[7] = d1 * acc[7] + 0.1f * e1.w;
            float m = v[0];
#pragma unroll
            for (int q = 1; q < 8; q++) m = fmaxf(m, v[q]);
#pragma unroll
            for (int off = 1; off < LPE; off <<= 1) m = fmaxf(m, __shfl_xor(m, off, 64));
            float ssum = 0.f;
#pragma unroll
            for (int q = 0; q < 8; q++) ssum += __expf(v[q] - m);
#pragma unroll
            for (int off = 1; off < LPE; off <<= 1) ssum += __shfl_xor(ssum, off, 64);
            float lse = m + __logf(ssum);
            float* o = (float*)out + (long)node * F + 8 * fl;
            float4 v0, v1;
            v0.x = v[0] - lse; v0.y = v[1] - lse; v0.z = v[2] - lse; v0.w = v[3] - lse;
            v1.x = v[4] - lse; v1.y = v[5] - lse; v1.z = v[6] - lse; v1.w = v[7] - lse;
            *(float4*)o = v0;
            *(float4*)(o + 4) = v1;
        }
    }
}

extern "C" void kernel_launch(void* const* d_in, const int* in_sizes, int n_in,
                              void* d_out, int out_size, void* d_ws, size_t ws_size,
                              hipStream_t stream) {
    const float* x  = (const float*)d_in[0];
    const int* edges = (const int*)d_in[1];
    const float* W1 = (const float*)d_in[2];
    const float* b1 = (const float*)d_in[3];
    const float* W2 = (const float*)d_in[4];
    const float* b2 = (const float*)d_in[5];
    const float* Wc = (const float*)d_in[6];
    const float* bc = (const float*)d_in[7];
    const float* We = (const float*)d_in[8];
    const float* be = (const float*)d_in[9];

    const int N = in_sizes[0] / 256;   // 100000
    const int E = in_sizes[1] / 2;     // 1600000
    const int* esrc = edges;
    const int* edst = edges + E;

    char* ws = (char*)d_ws;
    size_t off = 0;
    auto alloc = [&](size_t bytes) -> void* {
        void* p = ws + off;
        off += (bytes + 255) & ~(size_t)255;
        return p;
    };
    int*    deg     = (int*)alloc((size_t)N * 4);
    int*    row_ptr = (int*)alloc((size_t)(N + 1) * 4);
    float*  dinv    = (float*)alloc((size_t)N * 4);
    int*    bs      = (int*)alloc(4096 * 4);
    int*    rank    = (int*)alloc((size_t)E * 4);
    int*    csr_src = (int*)alloc((size_t)E * 4);
    __half* P       = (__half*)alloc((size_t)N * 128 * 2);  // f16 table A
    __half* Q16     = (__half*)alloc((size_t)N * 128 * 2);  // f16 table B
    __half* zA      = (__half*)alloc((size_t)N * 64 * 2);
    __half* zB      = (__half*)alloc((size_t)N * 64 * 2);
    __half* evs     = (__half*)alloc((size_t)N * 64 * 2);
    float*  bf      = (float*)alloc(64 * 4);
    __half* W1t     = (__half*)alloc(128 * 256 * 2);  // fragment-major
    __half* W2t     = (__half*)alloc(128 * 128 * 2);  // fragment-major
    __half* Wft     = (__half*)alloc(64 * 128 * 2);   // fragment-major
    float*  ev      = (float*)d_out;  // f32 ev lives in d_out until final step

    const int nbN = (N + 255) / 256;
    const int nbE = (E + 255) / 256;
    const int nbP = (N + 3) / 4;        // wave-per-node kernels
    const int TG  = (N + 127) / 128;    // GEMM/cls blocks (128 rows each)

    // --- prep + fat kernel: GEMM1 (unscaled) with fused edge count ---
    hipMemsetAsync(deg, 0, (size_t)N * 4, stream);
    k_prep<<<193, 256, 0, stream>>>(W1, W2, Wc, bc, We, be, W1t, W2t, Wft, bf);
    k_gemm<256, false, true><<<TG, 512, 0, stream>>>(x, W1t, nullptr, P, N,
                                                     edst, deg, rank, E);

    // --- CSR build ---
    k_scanA<<<nbN, 256, 0, stream>>>(deg, bs, N);
    k_scanB<<<1, 512, 0, stream>>>(bs, nbN);
    k_scanC<<<nbN, 256, 0, stream>>>(deg, bs, row_ptr, dinv, N);
    k_fill<<<nbE, 256, 0, stream>>>(esrc, edst, row_ptr, rank, csr_src, E);

    // --- GCN layer 1 prop (per-edge dinv: MODE 4, P unscaled) ---
    k_prop2<128, 4><<<nbP, 256, 0, stream>>>(P, row_ptr, csr_src, dinv, b1, nullptr, Q16, N);

    // --- GCN layer 2: P = f16(dinv * Q16@W2) via MFMA; prop MODE 3 ---
    k_gemm<128, true, false><<<TG, 512, 0, stream>>>(Q16, W2t, dinv, P, N,
                                                     nullptr, nullptr, nullptr, 0);
    k_prop2<128, 3><<<nbP, 256, 0, stream>>>(P, row_ptr, csr_src, dinv, b2, nullptr, Q16, N);

    // --- fused classifier (MFMA): ev (f32, d_out) + evs (f16 scaled) ---
    k_cls<<<TG, 512, 0, stream>>>(Q16, Wft, bf, dinv, ev, evs, N);

    // --- APPNP: 9 scaled f16 iterations + final step fused w/ log_softmax ---
    const __half* zin = evs;
    __half* zout;
    for (int it = 0; it < 9; ++it) {
        zout = (it % 2 == 0) ? zA : zB;
        k_prop2<64, 1><<<nbP, 256, 0, stream>>>(zin, row_ptr, csr_src, dinv, nullptr, evs, zout, N);
        zin = zout;
    }
    // final: reads zA(f16) + ev(f32,d_out), writes log_softmax rows to d_out
    k_prop2<64, 2><<<nbP, 256, 0, stream>>>(zin, row_ptr, csr_src, dinv, nullptr, ev, (float*)d_out, N);
}